// Round 14
// baseline (81.717 us; speedup 1.0000x reference)
//
#include <hip/hip_runtime.h>
#include <utility>

#define N_SAMP   4410000
#define WSZ      441
#define NC       10000
#define NB       500
#define LB       20           // NB*LB == NC
#define TILEF    (LB*WSZ)     // 8820 floats = full per-block fb tile (35.3 KB)
#define TWO_PI_F 6.28318530717958647692f
#define FADE_START (N_SAMP - 256)
#define INV_SR   (1.0f/44100.0f)
#define INV441   (1.0f/441.0f)

// workspace layout (floats)
#define WS_WT   0                          // 441 wavetable (padded 448)
#define WS_SLOT(a) (448 + (a)*448)         // a = 0..NB-2: Vhat_a ([0..220]=Re, [224..444]=Im); k_scan -> Shat_{a+1}
#define WS_NEED ((size_t)(448 + (NB-1)*448) * sizeof(float))

static_assert(NB * LB == NC, "block decomposition");

// ---- compile-time loop unroll (forces static indices -> registers, rule #20) ----
template <class F, int... Is>
__device__ __forceinline__ void unroll_impl(F f, std::integer_sequence<int, Is...>) {
    (f(std::integral_constant<int, Is>{}), ...);
}
template <int N, class F>
__device__ __forceinline__ void unroll_for(F f) {
    unroll_impl(f, std::make_integer_sequence<int, N>{});
}

// hardware trig: v_sin_f32/v_cos_f32 — input in REVOLUTIONS (sin/cos(2*pi*x)).
__device__ __forceinline__ float hwsin(float rev) { return __builtin_amdgcn_sinf(rev); }
__device__ __forceinline__ float hwcos(float rev) { return __builtin_amdgcn_cosf(rev); }

// async global->LDS: lane l copies 16B from its gsrc to ldsbase + l*16 (wave-uniform base).
__device__ __forceinline__ void gl2lds16(const float* gsrc_lane, float* lds_base_uniform) {
    __builtin_amdgcn_global_load_lds(
        (const __attribute__((address_space(1))) void*)gsrc_lane,
        (__attribute__((address_space(3))) void*)lds_base_uniform,
        16, 0, 0);
}

// stage nfloats (mult of 4) from g to l using all 4 waves; caller must __syncthreads() after.
__device__ __forceinline__ void stage_tile(const float* __restrict__ g,
                                           float* __restrict__ l,
                                           int nfloats, int tid) {
    const int wave = tid >> 6, lane = tid & 63;
    const int nfull = nfloats >> 8;              // 256-float (1 KiB) chunks
    for (int c = wave; c < nfull; c += 4)
        gl2lds16(g + (c << 8) + lane*4, l + (c << 8));
    const int rem = nfloats & 255;
    if (rem && wave == 0 && lane*4 < rem) {
        const int base = nfull << 8;
        gl2lds16(g + base + lane*4, l + base);
    }
}

__device__ __forceinline__ void bq_coefs(float f, float q,
    float& b0, float& b1, float& b2, float& a1, float& a2)
{
    float w0 = TWO_PI_F * f / 44100.0f;
    float cw = cosf(w0), sw = sinf(w0);
    float al = sw / (2.0f * q);
    float a0 = 1.0f + al;
    b0 = ((1.0f - cw) * 0.5f) / a0;
    b1 = (1.0f - cw) / a0;
    b2 = ((1.0f - cw) * 0.5f) / a0;
    a1 = (-2.0f * cw) / a0;
    a2 = (1.0f - al) / a0;
}

// serial biquad pair (fallback kernel only)
__device__ __forceinline__ void run_biquads(const float* __restrict__ noise,
    float lpf, float lpq, float f2, float* dst)
{
    float c10,c11,c12,c13,c14, c20,c21,c22,c23,c24;
    bq_coefs(lpf, lpq, c10,c11,c12,c13,c14);
    bq_coefs(f2, 0.707f, c20,c21,c22,c23,c24);
    float s11=0.f,s12=0.f,s21=0.f,s22=0.f;
    for (int m = 0; m < WSZ; ++m) {
        float x  = noise[m];
        float y1 = c10*x + s11;
        s11 = c11*x - c13*y1 + s12;
        s12 = c12*x - c14*y1;
        float y2 = c20*y1 + s21;
        s21 = c21*y1 - c23*y2 + s22;
        s22 = c22*y1 - c24*y2;
        dst[m] = y2;
    }
}

// redundant per-wave MLP: lane computes hid cols lane, lane+64; shfl_xor reduce -> lat[5]
__device__ __forceinline__ void mlp_latents(
    const float* __restrict__ h, const float* __restrict__ W1,
    const float* __restrict__ b1v, const float* __restrict__ W2,
    const float* __restrict__ b2v, int lane, float lat[5])
{
    float hc0 = b1v[lane], hc1 = b1v[lane + 64];
    #pragma unroll
    for (int i = 0; i < 9; ++i) {
        float hv = h[i];
        hc0 = fmaf(hv, W1[i*128 + lane], hc0);
        hc1 = fmaf(hv, W1[i*128 + lane + 64], hc1);
    }
    hc0 = fmaxf(hc0, 0.f); hc1 = fmaxf(hc1, 0.f);
    float part[5];
    #pragma unroll
    for (int m = 0; m < 5; ++m)
        part[m] = fmaf(hc0, W2[lane*5 + m], hc1 * W2[(lane+64)*5 + m]);
    #pragma unroll
    for (int off = 32; off > 0; off >>= 1) {
        #pragma unroll
        for (int m = 0; m < 5; ++m)
            part[m] += __shfl_xor(part[m], off);
    }
    #pragma unroll
    for (int m = 0; m < 5; ++m)
        lat[m] = fmaxf(part[m] + b2v[m], 0.f);
}

// wave-parallel biquad over 441 samples: lane l holds positions 7l..7l+6 (Kogge-Stone affine scan)
__device__ __forceinline__ void biquad_wave(const float xin[7], float yout[7],
    float f, float q, int l)
{
    float b0,b1,b2,a1,a2;
    bq_coefs(f, q, b0,b1,b2,a1,a2);
    const float t1c = b1 - a1*b0;
    const float t2c = b2 - a2*b0;
    float m00=1.f,m01=0.f,m10=0.f,m11=1.f;
    float cv0=0.f, cv1=0.f;
    #pragma unroll
    for (int k = 0; k < 7; ++k) {
        float x = xin[k];
        float n0 = -a1*cv0 + cv1 + t1c*x;
        float n1 = -a2*cv0 + t2c*x;
        cv0 = n0; cv1 = n1;
        float r00 = -a1*m00 + m10, r01 = -a1*m01 + m11;
        float r10 = -a2*m00,       r11 = -a2*m01;
        m00=r00; m01=r01; m10=r10; m11=r11;
    }
    #pragma unroll
    for (int d = 1; d < 64; d <<= 1) {
        int srcl = l - d; int s2 = srcl < 0 ? 0 : srcl;
        float pm00=__shfl(m00,s2), pm01=__shfl(m01,s2);
        float pm10=__shfl(m10,s2), pm11=__shfl(m11,s2);
        float pc0=__shfl(cv0,s2), pc1=__shfl(cv1,s2);
        if (srcl >= 0) {
            float nc0 = m00*pc0 + m01*pc1 + cv0;
            float nc1 = m10*pc0 + m11*pc1 + cv1;
            float n00 = m00*pm00 + m01*pm10;
            float n01 = m00*pm01 + m01*pm11;
            float n10 = m10*pm00 + m11*pm10;
            float n11 = m10*pm01 + m11*pm11;
            m00=n00; m01=n01; m10=n10; m11=n11; cv0=nc0; cv1=nc1;
        }
    }
    int esrc = (l == 0) ? 0 : l - 1;
    float e0 = __shfl(cv0, esrc);
    float e1 = __shfl(cv1, esrc);
    float s1  = (l == 0) ? 0.f : e0;
    float s2v = (l == 0) ? 0.f : e1;
    #pragma unroll
    for (int k = 0; k < 7; ++k) {
        float x = xin[k];
        float y = b0*x + s1;
        float ns1 = b1*x - a1*y + s2v;
        s2v = b2*x - a2*y;
        s1 = ns1;
        yout[k] = y;
    }
}

// batched DFT of v (in LDS) -> ws slot; modes 0..220
__device__ __forceinline__ void dft_to_ws(const float* v_lds, float* ws_slot, int tid)
{
    if (tid >= 221) return;
    const float srev = (float)tid * INV441;
    const float cstep = hwcos(srev);
    const float sstep = -hwsin(srev);            // e^{-2pi i tid/441}
    float ar = 0.f, ai = 0.f;
    const int t8 = (8*tid) % 441;
    int pm = 0;
    for (int g = 0; g < 55; ++g) {
        float4 va = *(const float4*)(v_lds + 8*g);
        float4 vb = *(const float4*)(v_lds + 8*g + 4);
        float prev = (float)pm * INV441;
        float wr = hwcos(prev);
        float wi = -hwsin(prev);
        float vv[8] = {va.x,va.y,va.z,va.w,vb.x,vb.y,vb.z,vb.w};
        #pragma unroll
        for (int k = 0; k < 8; ++k) {
            ar = fmaf(vv[k], wr, ar);
            ai = fmaf(vv[k], wi, ai);
            float nr = wr*cstep - wi*sstep;
            float ni = wr*sstep + wi*cstep;
            wr = nr; wi = ni;
        }
        pm += t8; if (pm >= 441) pm -= 441;
    }
    {   // tail m = 440
        float prev = (float)pm * INV441;
        float wr = hwcos(prev);
        float wi = -hwsin(prev);
        float v = v_lds[440];
        ar = fmaf(v, wr, ar);
        ai = fmaf(v, wi, ai);
    }
    ws_slot[tid]       = ar;
    ws_slot[224 + tid] = ai;
}

// batched IDFT of SrL/SiL (LDS) -> e_lds; two rows per thread
__device__ __forceinline__ void idft_to_elds(const float* SrL, const float* SiL,
                                             float* e_lds, int tid)
{
    const int m1 = tid;
    const int m2c = tid + 256;
    const bool has2 = (m2c < 441);
    const int m2 = has2 ? m2c : 0;
    const float s1c = hwcos((float)m1 * INV441), s1s = hwsin((float)m1 * INV441);
    const float s2c = hwcos((float)m2 * INV441), s2s = hwsin((float)m2 * INV441);
    float acc1 = 0.f, acc2 = 0.f;
    const int t8a = (8*m1) % 441;
    const int t8b = (8*m2) % 441;
    int pm1 = 0, pm2 = 0;
    for (int g = 0; g < 27; ++g) {
        float4 ra = *(const float4*)(SrL + 8*g);
        float4 rb = *(const float4*)(SrL + 8*g + 4);
        float4 ia = *(const float4*)(SiL + 8*g);
        float4 ib = *(const float4*)(SiL + 8*g + 4);
        float w1r = hwcos((float)pm1 * INV441), w1i = hwsin((float)pm1 * INV441);
        float w2r = hwcos((float)pm2 * INV441), w2i = hwsin((float)pm2 * INV441);
        float vr[8] = {ra.x,ra.y,ra.z,ra.w,rb.x,rb.y,rb.z,rb.w};
        float vi[8] = {ia.x,ia.y,ia.z,ia.w,ib.x,ib.y,ib.z,ib.w};
        #pragma unroll
        for (int k = 0; k < 8; ++k) {
            acc1 = fmaf(vr[k], w1r, acc1);
            acc1 = fmaf(-vi[k], w1i, acc1);
            float n1r = w1r*s1c - w1i*s1s;
            float n1i = w1r*s1s + w1i*s1c;
            w1r = n1r; w1i = n1i;
            acc2 = fmaf(vr[k], w2r, acc2);
            acc2 = fmaf(-vi[k], w2i, acc2);
            float n2r = w2r*s2c - w2i*s2s;
            float n2i = w2r*s2s + w2i*s2c;
            w2r = n2r; w2i = n2i;
        }
        pm1 += t8a; if (pm1 >= 441) pm1 -= 441;
        pm2 += t8b; if (pm2 >= 441) pm2 -= 441;
    }
    {   // tail jj = 216..220
        float w1r = hwcos((float)pm1 * INV441), w1i = hwsin((float)pm1 * INV441);
        float w2r = hwcos((float)pm2 * INV441), w2i = hwsin((float)pm2 * INV441);
        #pragma unroll
        for (int k = 0; k < 5; ++k) {
            float vr = SrL[216 + k], vi = SiL[216 + k];
            acc1 = fmaf(vr, w1r, acc1);
            acc1 = fmaf(-vi, w1i, acc1);
            float n1r = w1r*s1c - w1i*s1s;
            float n1i = w1r*s1s + w1i*s1c;
            w1r = n1r; w1i = n1i;
            acc2 = fmaf(vr, w2r, acc2);
            acc2 = fmaf(-vi, w2i, acc2);
            float n2r = w2r*s2c - w2i*s2s;
            float n2i = w2r*s2s + w2i*s2c;
            w2r = n2r; w2i = n2i;
        }
    }
    float s0v = SrL[0];
    e_lds[m1] = (2.0f*acc1 - s0v) * (1.0f/441.0f);
    if (has2) e_lds[m2c] = (2.0f*acc2 - s0v) * (1.0f/441.0f);
}

// ============ kernel 1: whole-tile async fb staging + local recurrence + DFT ============
// 2 blocks/CU: stalls in one block hide under the other block's compute.
__global__ __launch_bounds__(256, 2) void k_front(
    const float* __restrict__ fb, const float* __restrict__ h,
    const float* __restrict__ noise, const float* __restrict__ W1,
    const float* __restrict__ b1v, const float* __restrict__ W2,
    const float* __restrict__ b2v, const float* __restrict__ lpcut,
    float* __restrict__ ws)
{
    __shared__ __align__(16) float fbL[TILEF + 24];    // 35.4 KB, linear (global_load_lds dest)
    __shared__ __align__(16) float v_lds[448];
    const int b = blockIdx.x;              // 0..NB-2
    const int tid = threadIdx.x;
    const bool w0 = tid < 64;
    const int j = tid;                     // lane within wave 0
    const bool act = w0 && (j < 63);
    const int i0 = b * LB;

    // issue the ENTIRE tile's staging first; latency hides under MLP/biquad.
    stage_tile(fb + i0*WSZ, fbL, TILEF, tid);

    float lat[5];
    mlp_latents(h, W1, b1v, W2, b2v, tid & 63, lat);
    const float decay = fminf(fmaxf(lat[0]/10.0f + 0.9f, 0.9f), 0.999f);
    const float famt  = lat[3];
    const float d2 = 0.5f * decay;
    const int src = (j == 0) ? 62 : j - 1;

    float cur[7];
    #pragma unroll
    for (int k = 0; k < 7; ++k) cur[k] = 0.f;
    if (w0 && b == 0) {
        const float lpf = fminf(fmaxf(lat[1]*44100.0f/4.0f, 100.0f), 22049.0f);
        const float lpq = fminf(fmaxf(lat[2], 0.1f), 0.999f);
        const float f2  = lpcut[0];
        float xin[7], y1[7], y2[7];
        #pragma unroll
        for (int k = 0; k < 7; ++k) xin[k] = act ? noise[7*j + k] : 0.f;
        biquad_wave(xin, y1, lpf, lpq, j);
        biquad_wave(y1, y2, f2, 0.707f, j);
        #pragma unroll
        for (int k = 0; k < 7; ++k) {
            cur[k] = act ? y2[k] : 0.f;        // entry state = wavetable (same layout)
            if (act) ws[WS_WT + 7*j + k] = y2[k];
        }
    }
    __syncthreads();                           // staging drained here

    if (w0) {
        unroll_for<LB>([&](auto I) {
            constexpr int i = decltype(I)::value;
            float x[7];
            #pragma unroll
            for (int k = 0; k < 7; ++k) {
                float fv = act ? fbL[i*WSZ + 7*j + k] : 0.f;
                x[k] = fmaf(famt, fv, cur[k]);
            }
            float x6p = __shfl(x[6], src);     // position 7j-1; lane0 <- lane62 (pos 440)
            cur[0] = d2 * (x[0] + x6p);
            #pragma unroll
            for (int k = 1; k < 7; ++k)
                cur[k] = d2 * (x[k] + x[k-1]);
        });
        if (act) {
            #pragma unroll
            for (int k = 0; k < 7; ++k) v_lds[7*j + k] = cur[k];
        }
    }
    __syncthreads();

    dft_to_ws(v_lds, ws + WS_SLOT(b), tid);
}

// ============ kernel 2: boundary prefix scan Shat_{a+1} = P*Shat_a + Vhat_a (in-place) ============
__global__ __launch_bounds__(256, 1) void k_scan(
    const float* __restrict__ h, const float* __restrict__ W1,
    const float* __restrict__ b1v, const float* __restrict__ W2,
    const float* __restrict__ b2v, float* __restrict__ ws)
{
    const int tid = threadIdx.x;
    float lat[5];
    mlp_latents(h, W1, b1v, W2, b2v, tid & 63, lat);
    const float decay = fminf(fmaxf(lat[0]/10.0f + 0.9f, 0.9f), 0.999f);
    if (tid >= 221) return;
    const float s = hwsin((float)tid * INV441);
    const float c = hwcos((float)tid * INV441);
    float lr = 0.5f*decay*(1.0f + c);
    float li = -0.5f*decay*s;
    float pr = 1.0f, pi = 0.0f, br = lr, bi = li;
    int e = LB;
    while (e) {
        if (e & 1) { float t = pr*br - pi*bi; pi = pr*bi + pi*br; pr = t; }
        float t2 = br*br - bi*bi; bi = 2.0f*br*bi; br = t2;
        e >>= 1;
    }
    const int NV = NB - 1;
    float sr = 0.0f, si = 0.0f;
    float cr8[8], ci8[8];
    #pragma unroll
    for (int d = 0; d < 8; ++d) {
        int idx = (d < NV) ? d : NV-1;
        cr8[d] = ws[WS_SLOT(idx) + tid];
        ci8[d] = ws[WS_SLOT(idx) + 224 + tid];
    }
    for (int base = 0; base < NV; base += 8) {
        float nr8[8], ni8[8];
        #pragma unroll
        for (int d = 0; d < 8; ++d) {
            int idx = base + 8 + d; if (idx >= NV) idx = NV-1;
            nr8[d] = ws[WS_SLOT(idx) + tid];
            ni8[d] = ws[WS_SLOT(idx) + 224 + tid];
        }
        #pragma unroll
        for (int d = 0; d < 8; ++d) {
            int bb = base + d;
            if (bb < NV) {
                float t1 = pr*sr - pi*si + cr8[d];
                si = pr*si + pi*sr + ci8[d];
                sr = t1;
                ws[WS_SLOT(bb) + tid]       = sr;
                ws[WS_SLOT(bb) + 224 + tid] = si;
            }
        }
        #pragma unroll
        for (int d = 0; d < 8; ++d) { cr8[d] = nr8[d]; ci8[d] = ni8[d]; }
    }
}

// ============ kernel 3: whole-tile staging + own Shat + IDFT + recurrence + env/flush ============
__global__ __launch_bounds__(256, 2) void k_back(
    const float* __restrict__ fb, const float* __restrict__ h,
    const float* __restrict__ W1, const float* __restrict__ b1v,
    const float* __restrict__ W2, const float* __restrict__ b2v,
    const float* __restrict__ t_in, const float* __restrict__ envp,
    const float* __restrict__ fade, float* __restrict__ out,
    const float* __restrict__ ws)
{
    __shared__ __align__(16) float fbL[TILEF + 24];    // 35.4 KB
    __shared__ float out_lds[TILEF];                   // 35.3 KB
    __shared__ __align__(16) float e_lds[448];
    __shared__ __align__(16) float SrL[224];
    __shared__ __align__(16) float SiL[224];
    const int b = blockIdx.x;                          // 0..NB-1
    const int tid = threadIdx.x;
    const bool w0 = tid < 64;
    const int j = tid;
    const bool act = w0 && (j < 63);
    const int i0 = b * LB;

    float lat[5];
    mlp_latents(h, W1, b1v, W2, b2v, tid & 63, lat);
    const float decay = fminf(fmaxf(lat[0]/10.0f + 0.9f, 0.9f), 0.999f);
    const float famt  = lat[3];
    const float gain  = lat[4];
    const float d2 = 0.5f * decay;
    const int src = (j == 0) ? 62 : j - 1;

    // own entry state (k_scan result) or wavetable
    if (b == 0) {
        for (int m = tid; m < 441; m += 256) e_lds[m] = ws[WS_WT + m];
    } else if (tid < 221) {
        SrL[tid] = ws[WS_SLOT(b-1) + tid];
        SiL[tid] = ws[WS_SLOT(b-1) + 224 + tid];
    }
    __syncthreads();

    // issue whole-tile fb staging now; latency hides under the IDFT below
    stage_tile(fb + i0*WSZ, fbL, TILEF, tid);

    if (b >= 1) idft_to_elds(SrL, SiL, e_lds, tid);
    __syncthreads();                           // staging + IDFT both complete

    const float a_  = fabsf(envp[0]) + 1e-3f;
    const float sus = envp[1];
    const float rr  = fabsf(envp[2]) + 1e-3f;
    const float inv_a = 1.0f / a_;
    const float inv_r = 1.0f / rr;
    const float sg = sus * gain;
    const float T = t_in[N_SAMP - 1];

    float cur[7];
    #pragma unroll
    for (int k = 0; k < 7; ++k)
        cur[k] = act ? e_lds[7*j + k] : 0.f;

    if (w0) {
        unroll_for<LB>([&](auto I) {
            constexpr int i = decltype(I)::value;
            float x[7];
            #pragma unroll
            for (int k = 0; k < 7; ++k) {
                float fv = act ? fbL[i*WSZ + 7*j + k] : 0.f;
                x[k] = fmaf(famt, fv, cur[k]);
            }
            float x6p = __shfl(x[6], src);
            cur[0] = d2 * (x[0] + x6p);
            #pragma unroll
            for (int k = 1; k < 7; ++k)
                cur[k] = d2 * (x[k] + x[k-1]);
            if (act) {
                #pragma unroll
                for (int k = 0; k < 7; ++k)
                    out_lds[i*WSZ + 7*j + k] = cur[k];
            }
        });
    }
    __syncthreads();

    // flush: all 256 threads, coalesced, env/fade/gain fused
    {
        const int s0 = i0 * WSZ;
        const float t_lo = (float)s0 * INV_SR;
        const float t_hi = (float)(s0 + TILEF - 1) * INV_SR;
        const bool fastenv = (t_lo * inv_a >= 1.0f) &&
                             ((T - t_hi) * inv_r >= 1.0f) &&
                             (s0 + TILEF <= FADE_START);
        if (fastenv) {
            for (int e = tid; e < TILEF; e += 256)
                out[s0 + e] = out_lds[e] * sg;
        } else {
            for (int e = tid; e < TILEF; e += 256) {
                const int idx = s0 + e;
                float tt = (float)idx * INV_SR;           // exact int->float: idx < 2^23
                float ca  = fminf(tt * inv_a, 1.0f);
                float crr = fminf(fmaxf((T - tt) * inv_r, 0.0f), 1.0f);
                float val = out_lds[e] * (ca * crr * sg);
                if (idx >= FADE_START) val *= fade[idx - FADE_START];
                out[idx] = val;
            }
        }
    }
}

// ---------------- fallback: fully sequential single block (no workspace) ----------
__global__ __launch_bounds__(448) void k_naive(
    const float* __restrict__ fb, const float* __restrict__ h,
    const float* __restrict__ t_in, const float* __restrict__ noise,
    const float* __restrict__ W1, const float* __restrict__ b1v,
    const float* __restrict__ W2, const float* __restrict__ b2v,
    const float* __restrict__ lpcut, const float* __restrict__ envp,
    const float* __restrict__ fade, float* __restrict__ out)
{
    __shared__ float hid[128];
    __shared__ float lat[5];
    __shared__ float wt[WSZ];
    __shared__ float buf[2][448];
    const int j = threadIdx.x;
    if (j < 128) {
        float acc = b1v[j];
        #pragma unroll
        for (int i = 0; i < 9; ++i) acc = acc + h[i] * W1[i*128 + j];
        hid[j] = fmaxf(acc, 0.0f);
    }
    __syncthreads();
    if (j < 5) {
        float a = b2v[j];
        for (int k = 0; k < 128; ++k) a = a + hid[k] * W2[k*5 + j];
        lat[j] = fmaxf(a, 0.0f);
    }
    __syncthreads();
    if (j == 0) {
        float lpf = fminf(fmaxf(lat[1]*44100.0f/4.0f, 100.0f), 22049.0f);
        float lpq = fminf(fmaxf(lat[2], 0.1f), 0.999f);
        run_biquads(noise, lpf, lpq, lpcut[0], wt);
    }
    __syncthreads();
    const float decay = fminf(fmaxf(lat[0]/10.0f + 0.9f, 0.9f), 0.999f);
    const float famt = lat[3];
    const float gain = lat[4];
    const float d2 = 0.5f * decay;
    const float a_  = fabsf(envp[0]) + 1e-3f;
    const float sus = envp[1];
    const float rr  = fabsf(envp[2]) + 1e-3f;
    const float inv_a = 1.0f / a_, inv_r = 1.0f / rr;
    const float T = t_in[N_SAMP - 1];
    const bool act = j < WSZ;
    const int jm1 = (j == 0) ? (WSZ - 1) : (j - 1);
    float cur = act ? wt[j] : 0.0f;
    for (int i = 0; i < NC; ++i) {
        float x = cur + famt * (act ? fb[i*WSZ + j] : 0.0f);
        buf[i&1][j] = x;
        __syncthreads();
        cur = d2 * (x + buf[i&1][jm1]);
        const int idx = i*WSZ + j;
        float val = cur;
        if (idx >= FADE_START) val *= fade[idx - FADE_START];
        float tt = act ? t_in[idx] : 0.0f;
        float ca  = fminf(fmaxf(tt * inv_a, 0.0f), 1.0f);
        float cr2 = fminf(fmaxf((T - tt) * inv_r, 0.0f), 1.0f);
        val = val * (ca * cr2 * sus) * gain;
        if (act) out[idx] = val;
    }
}

extern "C" void kernel_launch(void* const* d_in, const int* in_sizes, int n_in,
                              void* d_out, int out_size, void* d_ws, size_t ws_size,
                              hipStream_t stream) {
    const float* fb   = (const float*)d_in[0];
    const float* h    = (const float*)d_in[1];
    const float* t    = (const float*)d_in[2];
    const float* nz   = (const float*)d_in[3];
    const float* W1   = (const float*)d_in[4];
    const float* b1v  = (const float*)d_in[5];
    const float* W2   = (const float*)d_in[6];
    const float* b2v  = (const float*)d_in[7];
    const float* lpc  = (const float*)d_in[8];
    const float* envp = (const float*)d_in[9];
    const float* fade = (const float*)d_in[10];
    float* out = (float*)d_out;
    float* ws  = (float*)d_ws;

    if (ws_size < WS_NEED) {
        k_naive<<<1, 448, 0, stream>>>(fb, h, t, nz, W1, b1v, W2, b2v, lpc, envp, fade, out);
        return;
    }
    k_front<<<NB-1, 256, 0, stream>>>(fb, h, nz, W1, b1v, W2, b2v, lpc, ws);
    k_scan <<<1,    256, 0, stream>>>(h, W1, b1v, W2, b2v, ws);
    k_back <<<NB,   256, 0, stream>>>(fb, h, W1, b1v, W2, b2v, t, envp, fade, out, ws);
}

// Round 15
// 54.174 us; speedup vs baseline: 1.5084x; 1.5084x over previous
//
#include <hip/hip_runtime.h>
#include <utility>

#define N_SAMP   4410000
#define WSZ      441
#define NC       10000
#define NB       250
#define LB       40           // NB*LB == NC
#define HB       20           // half-block flush granularity
#define TILEF    (LB*WSZ)     // 17640 floats = per-block fb tile (70.6 KB)
#define RD       16           // k_scan prefetch ring depth
#define TWO_PI_F 6.28318530717958647692f
#define FADE_START (N_SAMP - 256)
#define INV_SR   (1.0f/44100.0f)
#define INV441   (1.0f/441.0f)

// workspace layout (floats)
#define WS_WT   0                          // 441 wavetable (padded 448)
#define WS_SLOT(a) (448 + (a)*448)         // a = 0..NB-2: Vhat_a ([0..220]=Re, [224..444]=Im); k_scan -> Shat_{a+1}
#define WS_NEED ((size_t)(448 + (NB-1)*448) * sizeof(float))

static_assert(NB * LB == NC, "block decomposition");
static_assert(LB == 2*HB, "two flush phases");

// ---- compile-time loop unroll (forces static indices -> registers, rule #20) ----
template <class F, int... Is>
__device__ __forceinline__ void unroll_impl(F f, std::integer_sequence<int, Is...>) {
    (f(std::integral_constant<int, Is>{}), ...);
}
template <int N, class F>
__device__ __forceinline__ void unroll_for(F f) {
    unroll_impl(f, std::make_integer_sequence<int, N>{});
}

// hardware trig: v_sin_f32/v_cos_f32 — input in REVOLUTIONS (sin/cos(2*pi*x)).
__device__ __forceinline__ float hwsin(float rev) { return __builtin_amdgcn_sinf(rev); }
__device__ __forceinline__ float hwcos(float rev) { return __builtin_amdgcn_cosf(rev); }

// async global->LDS: lane l copies 16B from its gsrc to ldsbase + l*16 (wave-uniform base).
__device__ __forceinline__ void gl2lds16(const float* gsrc_lane, float* lds_base_uniform) {
    __builtin_amdgcn_global_load_lds(
        (const __attribute__((address_space(1))) void*)gsrc_lane,
        (__attribute__((address_space(3))) void*)lds_base_uniform,
        16, 0, 0);
}

// stage nfloats from g to l using 7 waves (448 threads); caller must __syncthreads() after.
__device__ __forceinline__ void stage_tile7(const float* __restrict__ g,
                                            float* __restrict__ l,
                                            int nfloats, int tid) {
    const int wave = tid >> 6, lane = tid & 63;
    const int nfull = nfloats >> 8;              // 256-float (1 KiB) chunks
    for (int c = wave; c < nfull; c += 7)
        gl2lds16(g + (c << 8) + lane*4, l + (c << 8));
    const int rem = nfloats & 255;
    if (rem && wave == 0 && lane*4 < rem) {
        const int base = nfull << 8;
        gl2lds16(g + base + lane*4, l + base);
    }
}

__device__ __forceinline__ void bq_coefs(float f, float q,
    float& b0, float& b1, float& b2, float& a1, float& a2)
{
    float w0 = TWO_PI_F * f / 44100.0f;
    float cw = cosf(w0), sw = sinf(w0);
    float al = sw / (2.0f * q);
    float a0 = 1.0f + al;
    b0 = ((1.0f - cw) * 0.5f) / a0;
    b1 = (1.0f - cw) / a0;
    b2 = ((1.0f - cw) * 0.5f) / a0;
    a1 = (-2.0f * cw) / a0;
    a2 = (1.0f - al) / a0;
}

// serial biquad pair (fallback kernel only)
__device__ __forceinline__ void run_biquads(const float* __restrict__ noise,
    float lpf, float lpq, float f2, float* dst)
{
    float c10,c11,c12,c13,c14, c20,c21,c22,c23,c24;
    bq_coefs(lpf, lpq, c10,c11,c12,c13,c14);
    bq_coefs(f2, 0.707f, c20,c21,c22,c23,c24);
    float s11=0.f,s12=0.f,s21=0.f,s22=0.f;
    for (int m = 0; m < WSZ; ++m) {
        float x  = noise[m];
        float y1 = c10*x + s11;
        s11 = c11*x - c13*y1 + s12;
        s12 = c12*x - c14*y1;
        float y2 = c20*y1 + s21;
        s21 = c21*y1 - c23*y2 + s22;
        s22 = c22*y1 - c24*y2;
        dst[m] = y2;
    }
}

// redundant per-wave MLP: lane computes hid cols lane, lane+64; shfl_xor reduce -> lat[5]
__device__ __forceinline__ void mlp_latents(
    const float* __restrict__ h, const float* __restrict__ W1,
    const float* __restrict__ b1v, const float* __restrict__ W2,
    const float* __restrict__ b2v, int lane, float lat[5])
{
    float hc0 = b1v[lane], hc1 = b1v[lane + 64];
    #pragma unroll
    for (int i = 0; i < 9; ++i) {
        float hv = h[i];
        hc0 = fmaf(hv, W1[i*128 + lane], hc0);
        hc1 = fmaf(hv, W1[i*128 + lane + 64], hc1);
    }
    hc0 = fmaxf(hc0, 0.f); hc1 = fmaxf(hc1, 0.f);
    float part[5];
    #pragma unroll
    for (int m = 0; m < 5; ++m)
        part[m] = fmaf(hc0, W2[lane*5 + m], hc1 * W2[(lane+64)*5 + m]);
    #pragma unroll
    for (int off = 32; off > 0; off >>= 1) {
        #pragma unroll
        for (int m = 0; m < 5; ++m)
            part[m] += __shfl_xor(part[m], off);
    }
    #pragma unroll
    for (int m = 0; m < 5; ++m)
        lat[m] = fmaxf(part[m] + b2v[m], 0.f);
}

// wave-parallel biquad over 441 samples: lane l holds positions 7l..7l+6 (Kogge-Stone affine scan)
__device__ __forceinline__ void biquad_wave(const float xin[7], float yout[7],
    float f, float q, int l)
{
    float b0,b1,b2,a1,a2;
    bq_coefs(f, q, b0,b1,b2,a1,a2);
    const float t1c = b1 - a1*b0;
    const float t2c = b2 - a2*b0;
    float m00=1.f,m01=0.f,m10=0.f,m11=1.f;
    float cv0=0.f, cv1=0.f;
    #pragma unroll
    for (int k = 0; k < 7; ++k) {
        float x = xin[k];
        float n0 = -a1*cv0 + cv1 + t1c*x;
        float n1 = -a2*cv0 + t2c*x;
        cv0 = n0; cv1 = n1;
        float r00 = -a1*m00 + m10, r01 = -a1*m01 + m11;
        float r10 = -a2*m00,       r11 = -a2*m01;
        m00=r00; m01=r01; m10=r10; m11=r11;
    }
    #pragma unroll
    for (int d = 1; d < 64; d <<= 1) {
        int srcl = l - d; int s2 = srcl < 0 ? 0 : srcl;
        float pm00=__shfl(m00,s2), pm01=__shfl(m01,s2);
        float pm10=__shfl(m10,s2), pm11=__shfl(m11,s2);
        float pc0=__shfl(cv0,s2), pc1=__shfl(cv1,s2);
        if (srcl >= 0) {
            float nc0 = m00*pc0 + m01*pc1 + cv0;
            float nc1 = m10*pc0 + m11*pc1 + cv1;
            float n00 = m00*pm00 + m01*pm10;
            float n01 = m00*pm01 + m01*pm11;
            float n10 = m10*pm00 + m11*pm10;
            float n11 = m10*pm01 + m11*pm11;
            m00=n00; m01=n01; m10=n10; m11=n11; cv0=nc0; cv1=nc1;
        }
    }
    int esrc = (l == 0) ? 0 : l - 1;
    float e0 = __shfl(cv0, esrc);
    float e1 = __shfl(cv1, esrc);
    float s1  = (l == 0) ? 0.f : e0;
    float s2v = (l == 0) ? 0.f : e1;
    #pragma unroll
    for (int k = 0; k < 7; ++k) {
        float x = xin[k];
        float y = b0*x + s1;
        float ns1 = b1*x - a1*y + s2v;
        s2v = b2*x - a2*y;
        s1 = ns1;
        yout[k] = y;
    }
}

// ---------- 441-pt forward FFT (21x21 Cooley-Tukey), real input in v, modes 0..220 -> ws slot ----------
// Forward: X[c+21d] = sum_b W441^{bc} W21^{bd} sum_a v[21a+b] W21^{ac}   (W = e^{-2pi i /N})
// Thread maps: stage1 t=(b*21+c) (21 lanes per b read same v addr -> broadcast);
//              stage2 t=(c*21+d) (21 lanes per c read same Z addr -> broadcast).
__device__ __forceinline__ void fft441_fwd(const float* v, float* Zr, float* Zi,
    const float* c441, const float* s441, float* ws_slot, int tid)
{
    if (tid < 441) {
        const int bq = tid / 21, c = tid - 21*bq;
        float yr = 0.f, yi = 0.f;
        int pm = 0;                                // (a*c) % 21
        #pragma unroll
        for (int a = 0; a < 21; ++a) {
            float x = v[21*a + bq];
            float cc = c441[21*pm], ss = s441[21*pm];
            yr = fmaf(x,  cc, yr);
            yi = fmaf(-x, ss, yi);
            pm += c; if (pm >= 21) pm -= 21;
        }
        const int bc = bq * c;                     // <= 400 < 441
        float cB = c441[bc], sB = s441[bc];
        Zr[c*21 + bq] = yr*cB + yi*sB;             // Z = Y * (cB - i sB)
        Zi[c*21 + bq] = yi*cB - yr*sB;
    }
    __syncthreads();
    if (tid < 441) {
        const int c = tid / 21, d = tid - 21*c;
        float xr = 0.f, xi = 0.f;
        int pm = 0;                                // (b*d) % 21
        const float* zr = Zr + c*21;
        const float* zi = Zi + c*21;
        #pragma unroll
        for (int bq = 0; bq < 21; ++bq) {
            float cc = c441[21*pm], ss = s441[21*pm];
            float gr = zr[bq], gi = zi[bq];
            xr = fmaf(gr, cc, fmaf(gi,  ss, xr));  // X += Z * (cc - i ss)
            xi = fmaf(gi, cc, fmaf(-gr, ss, xi));
            pm += d; if (pm >= 21) pm -= 21;
        }
        const int jm = c + 21*d;
        if (jm < 221) {
            ws_slot[jm]       = xr;
            ws_slot[224 + jm] = xi;
        }
    }
}

// ---------- 441-pt inverse FFT: full-spectrum S (conj-extended) -> real e_lds; scaled 1/441 ----------
__device__ __forceinline__ void fft441_inv(const float* SrF, const float* SiF,
    float* Hr, float* Hi, const float* c441, const float* s441,
    float* e_lds, int tid)
{
    if (tid < 441) {
        const int bq = tid / 21, c = tid - 21*bq;
        float gr = 0.f, gi = 0.f;
        int pm = 0;                                // (a*c) % 21
        #pragma unroll
        for (int a = 0; a < 21; ++a) {
            float sr = SrF[21*a + bq], si = SiF[21*a + bq];
            float cc = c441[21*pm], ss = s441[21*pm];
            gr = fmaf(sr, cc, fmaf(-si, ss, gr));  // G += S * (cc + i ss)
            gi = fmaf(sr, ss, fmaf( si, cc, gi));
            pm += c; if (pm >= 21) pm -= 21;
        }
        const int bc = bq * c;
        float cB = c441[bc], sB = s441[bc];
        Hr[c*21 + bq] = gr*cB - gi*sB;             // H = G * (cB + i sB)
        Hi[c*21 + bq] = gr*sB + gi*cB;
    }
    __syncthreads();
    if (tid < 441) {
        const int c = tid / 21, d = tid - 21*c;
        float acc = 0.f;
        int pm = 0;                                // (b*d) % 21
        const float* hr = Hr + c*21;
        const float* hi = Hi + c*21;
        #pragma unroll
        for (int bq = 0; bq < 21; ++bq) {
            float cc = c441[21*pm], ss = s441[21*pm];
            acc = fmaf(hr[bq], cc, fmaf(-hi[bq], ss, acc));  // Re(H * (cc + i ss))
            pm += d; if (pm >= 21) pm -= 21;
        }
        e_lds[c + 21*d] = acc * (1.0f/441.0f);
    }
}

// ============ kernel 1: whole-tile staging + local recurrence + forward FFT ============
__global__ __launch_bounds__(448, 1) void k_front(
    const float* __restrict__ fb, const float* __restrict__ h,
    const float* __restrict__ noise, const float* __restrict__ W1,
    const float* __restrict__ b1v, const float* __restrict__ W2,
    const float* __restrict__ b2v, const float* __restrict__ lpcut,
    float* __restrict__ ws)
{
    __shared__ __align__(16) float fbL[TILEF + 24];    // 70.7 KB
    __shared__ __align__(16) float v_lds[448];
    __shared__ __align__(16) float Zr[441], Zi[441];
    __shared__ float c441[441], s441[441];
    const int b = blockIdx.x;              // 0..NB-2
    const int tid = threadIdx.x;
    const bool w0 = tid < 64;
    const int j = tid;
    const bool act = w0 && (j < 63);
    const int i0 = b * LB;

    stage_tile7(fb + i0*WSZ, fbL, TILEF, tid);   // issue first; drains at 1st barrier
    if (tid < 441) {
        float ph = (float)tid * INV441;
        c441[tid] = hwcos(ph);
        s441[tid] = hwsin(ph);
    }

    float lat[5];
    mlp_latents(h, W1, b1v, W2, b2v, tid & 63, lat);
    const float decay = fminf(fmaxf(lat[0]/10.0f + 0.9f, 0.9f), 0.999f);
    const float famt  = lat[3];
    const float d2 = 0.5f * decay;
    const int src = (j == 0) ? 62 : j - 1;

    float cur[7];
    #pragma unroll
    for (int k = 0; k < 7; ++k) cur[k] = 0.f;
    if (w0 && b == 0) {
        const float lpf = fminf(fmaxf(lat[1]*44100.0f/4.0f, 100.0f), 22049.0f);
        const float lpq = fminf(fmaxf(lat[2], 0.1f), 0.999f);
        const float f2  = lpcut[0];
        float xin[7], y1[7], y2[7];
        #pragma unroll
        for (int k = 0; k < 7; ++k) xin[k] = act ? noise[7*j + k] : 0.f;
        biquad_wave(xin, y1, lpf, lpq, j);
        biquad_wave(y1, y2, f2, 0.707f, j);
        #pragma unroll
        for (int k = 0; k < 7; ++k) {
            cur[k] = act ? y2[k] : 0.f;
            if (act) ws[WS_WT + 7*j + k] = y2[k];
        }
    }
    __syncthreads();                           // staging drained; tables ready

    if (w0) {
        unroll_for<LB>([&](auto I) {
            constexpr int i = decltype(I)::value;
            float x[7];
            #pragma unroll
            for (int k = 0; k < 7; ++k) {
                float fv = act ? fbL[i*WSZ + 7*j + k] : 0.f;
                x[k] = fmaf(famt, fv, cur[k]);
            }
            float x6p = __shfl(x[6], src);     // pos 7j-1; lane0 <- lane62 (pos 440)
            cur[0] = d2 * (x[0] + x6p);
            #pragma unroll
            for (int k = 1; k < 7; ++k)
                cur[k] = d2 * (x[k] + x[k-1]);
        });
        if (act) {
            #pragma unroll
            for (int k = 0; k < 7; ++k) v_lds[7*j + k] = cur[k];
        }
    }
    __syncthreads();

    fft441_fwd(v_lds, Zr, Zi, c441, s441, ws + WS_SLOT(b), tid);
}

// ============ kernel 2: boundary prefix scan Shat_{a+1} = P*Shat_a + Vhat_a (in-place) ============
__global__ __launch_bounds__(256, 1) void k_scan(
    const float* __restrict__ h, const float* __restrict__ W1,
    const float* __restrict__ b1v, const float* __restrict__ W2,
    const float* __restrict__ b2v, float* __restrict__ ws)
{
    const int tid = threadIdx.x;
    float lat[5];
    mlp_latents(h, W1, b1v, W2, b2v, tid & 63, lat);
    const float decay = fminf(fmaxf(lat[0]/10.0f + 0.9f, 0.9f), 0.999f);
    if (tid >= 221) return;
    const float s = hwsin((float)tid * INV441);
    const float c = hwcos((float)tid * INV441);
    float lr = 0.5f*decay*(1.0f + c);
    float li = -0.5f*decay*s;
    float pr = 1.0f, pi = 0.0f, br = lr, bi = li;   // P = lambda^LB
    int e = LB;
    while (e) {
        if (e & 1) { float t = pr*br - pi*bi; pi = pr*bi + pi*br; pr = t; }
        float t2 = br*br - bi*bi; bi = 2.0f*br*bi; br = t2;
        e >>= 1;
    }
    const int NV = NB - 1;                 // 249
    float sr = 0.0f, si = 0.0f;
    float cr[RD], ci[RD];
    #pragma unroll
    for (int d = 0; d < RD; ++d) {
        int idx = (d < NV) ? d : NV-1;
        cr[d] = ws[WS_SLOT(idx) + tid];
        ci[d] = ws[WS_SLOT(idx) + 224 + tid];
    }
    for (int base = 0; base < NV; base += RD) {
        float nr[RD], ni[RD];
        #pragma unroll
        for (int d = 0; d < RD; ++d) {
            int idx = base + RD + d; if (idx >= NV) idx = NV-1;
            nr[d] = ws[WS_SLOT(idx) + tid];
            ni[d] = ws[WS_SLOT(idx) + 224 + tid];
        }
        #pragma unroll
        for (int d = 0; d < RD; ++d) {
            int bb = base + d;
            if (bb < NV) {
                float t1 = pr*sr - pi*si + cr[d];
                si = pr*si + pi*sr + ci[d];
                sr = t1;
                ws[WS_SLOT(bb) + tid]       = sr;
                ws[WS_SLOT(bb) + 224 + tid] = si;
            }
        }
        #pragma unroll
        for (int d = 0; d < RD; ++d) { cr[d] = nr[d]; ci[d] = ni[d]; }
    }
}

// ============ kernel 3: staging + own Shat + inverse FFT + recurrence + env/flush ============
__global__ __launch_bounds__(448, 1) void k_back(
    const float* __restrict__ fb, const float* __restrict__ h,
    const float* __restrict__ W1, const float* __restrict__ b1v,
    const float* __restrict__ W2, const float* __restrict__ b2v,
    const float* __restrict__ t_in, const float* __restrict__ envp,
    const float* __restrict__ fade, float* __restrict__ out,
    const float* __restrict__ ws)
{
    __shared__ __align__(16) float fbL[TILEF + 24];    // 70.7 KB
    __shared__ float out_lds[HB*441];                  // 35.3 KB
    __shared__ __align__(16) float SrF[441], SiF[441];
    __shared__ __align__(16) float Hr[441], Hi[441];
    __shared__ __align__(16) float e_lds[448];
    __shared__ float c441[441], s441[441];
    const int b = blockIdx.x;                          // 0..NB-1
    const int tid = threadIdx.x;
    const bool w0 = tid < 64;
    const int j = tid;
    const bool act = w0 && (j < 63);
    const int i0 = b * LB;

    if (tid < 441) {
        float ph = (float)tid * INV441;
        c441[tid] = hwcos(ph);
        s441[tid] = hwsin(ph);
    }

    float lat[5];
    mlp_latents(h, W1, b1v, W2, b2v, tid & 63, lat);
    const float decay = fminf(fmaxf(lat[0]/10.0f + 0.9f, 0.9f), 0.999f);
    const float famt  = lat[3];
    const float gain  = lat[4];
    const float d2 = 0.5f * decay;
    const int src = (j == 0) ? 62 : j - 1;

    stage_tile7(fb + i0*WSZ, fbL, TILEF, tid);   // issue early; drains at barriers below

    if (b == 0) {
        for (int m = tid; m < 441; m += 448) e_lds[m] = ws[WS_WT + m];
        __syncthreads();
    } else {
        if (tid < 221) {                        // own entry state, computed by k_scan
            SrF[tid] = ws[WS_SLOT(b-1) + tid];
            SiF[tid] = ws[WS_SLOT(b-1) + 224 + tid];
        }
        __syncthreads();
        if (tid >= 221 && tid < 441) {          // conj extension: S[j] = conj(S[441-j])
            SrF[tid] =  SrF[441 - tid];
            SiF[tid] = -SiF[441 - tid];
        }
        __syncthreads();
        fft441_inv(SrF, SiF, Hr, Hi, c441, s441, e_lds, tid);
        __syncthreads();
    }

    const float a_  = fabsf(envp[0]) + 1e-3f;
    const float sus = envp[1];
    const float rr  = fabsf(envp[2]) + 1e-3f;
    const float inv_a = 1.0f / a_;
    const float inv_r = 1.0f / rr;
    const float sg = sus * gain;
    const float T = t_in[N_SAMP - 1];

    float cur[7];
    #pragma unroll
    for (int k = 0; k < 7; ++k)
        cur[k] = act ? e_lds[7*j + k] : 0.f;

    auto compute_half = [&](auto PH) {
        constexpr int ph = decltype(PH)::value;
        if (w0) {
            unroll_for<HB>([&](auto I) {
                constexpr int il = decltype(I)::value;
                constexpr int i = ph*HB + il;
                float x[7];
                #pragma unroll
                for (int k = 0; k < 7; ++k) {
                    float fv = act ? fbL[i*WSZ + 7*j + k] : 0.f;
                    x[k] = fmaf(famt, fv, cur[k]);
                }
                float x6p = __shfl(x[6], src);
                cur[0] = d2 * (x[0] + x6p);
                #pragma unroll
                for (int k = 1; k < 7; ++k)
                    cur[k] = d2 * (x[k] + x[k-1]);
                if (act) {
                    #pragma unroll
                    for (int k = 0; k < 7; ++k)
                        out_lds[il*WSZ + 7*j + k] = cur[k];
                }
            });
        }
    };
    auto flush = [&](int ph) {
        const int s0 = (i0 + ph*HB) * WSZ;
        const float t_lo = (float)s0 * INV_SR;
        const float t_hi = (float)(s0 + HB*WSZ - 1) * INV_SR;
        const bool fastenv = (t_lo * inv_a >= 1.0f) &&
                             ((T - t_hi) * inv_r >= 1.0f) &&
                             (s0 + HB*WSZ <= FADE_START);
        if (fastenv) {
            for (int e = tid; e < HB*WSZ; e += 448)
                out[s0 + e] = out_lds[e] * sg;
        } else {
            for (int e = tid; e < HB*WSZ; e += 448) {
                const int idx = s0 + e;
                float tt = (float)idx * INV_SR;           // exact int->float: idx < 2^23
                float ca  = fminf(tt * inv_a, 1.0f);
                float crr = fminf(fmaxf((T - tt) * inv_r, 0.0f), 1.0f);
                float val = out_lds[e] * (ca * crr * sg);
                if (idx >= FADE_START) val *= fade[idx - FADE_START];
                out[idx] = val;
            }
        }
    };

    compute_half(std::integral_constant<int,0>{});
    __syncthreads();
    flush(0);
    __syncthreads();
    compute_half(std::integral_constant<int,1>{});
    __syncthreads();
    flush(1);
}

// ---------------- fallback: fully sequential single block (no workspace) ----------
__global__ __launch_bounds__(448) void k_naive(
    const float* __restrict__ fb, const float* __restrict__ h,
    const float* __restrict__ t_in, const float* __restrict__ noise,
    const float* __restrict__ W1, const float* __restrict__ b1v,
    const float* __restrict__ W2, const float* __restrict__ b2v,
    const float* __restrict__ lpcut, const float* __restrict__ envp,
    const float* __restrict__ fade, float* __restrict__ out)
{
    __shared__ float hid[128];
    __shared__ float lat[5];
    __shared__ float wt[WSZ];
    __shared__ float buf[2][448];
    const int j = threadIdx.x;
    if (j < 128) {
        float acc = b1v[j];
        #pragma unroll
        for (int i = 0; i < 9; ++i) acc = acc + h[i] * W1[i*128 + j];
        hid[j] = fmaxf(acc, 0.0f);
    }
    __syncthreads();
    if (j < 5) {
        float a = b2v[j];
        for (int k = 0; k < 128; ++k) a = a + hid[k] * W2[k*5 + j];
        lat[j] = fmaxf(a, 0.0f);
    }
    __syncthreads();
    if (j == 0) {
        float lpf = fminf(fmaxf(lat[1]*44100.0f/4.0f, 100.0f), 22049.0f);
        float lpq = fminf(fmaxf(lat[2], 0.1f), 0.999f);
        run_biquads(noise, lpf, lpq, lpcut[0], wt);
    }
    __syncthreads();
    const float decay = fminf(fmaxf(lat[0]/10.0f + 0.9f, 0.9f), 0.999f);
    const float famt = lat[3];
    const float gain = lat[4];
    const float d2 = 0.5f * decay;
    const float a_  = fabsf(envp[0]) + 1e-3f;
    const float sus = envp[1];
    const float rr  = fabsf(envp[2]) + 1e-3f;
    const float inv_a = 1.0f / a_, inv_r = 1.0f / rr;
    const float T = t_in[N_SAMP - 1];
    const bool act = j < WSZ;
    const int jm1 = (j == 0) ? (WSZ - 1) : (j - 1);
    float cur = act ? wt[j] : 0.0f;
    for (int i = 0; i < NC; ++i) {
        float x = cur + famt * (act ? fb[i*WSZ + j] : 0.0f);
        buf[i&1][j] = x;
        __syncthreads();
        cur = d2 * (x + buf[i&1][jm1]);
        const int idx = i*WSZ + j;
        float val = cur;
        if (idx >= FADE_START) val *= fade[idx - FADE_START];
        float tt = act ? t_in[idx] : 0.0f;
        float ca  = fminf(fmaxf(tt * inv_a, 0.0f), 1.0f);
        float cr2 = fminf(fmaxf((T - tt) * inv_r, 0.0f), 1.0f);
        val = val * (ca * cr2 * sus) * gain;
        if (act) out[idx] = val;
    }
}

extern "C" void kernel_launch(void* const* d_in, const int* in_sizes, int n_in,
                              void* d_out, int out_size, void* d_ws, size_t ws_size,
                              hipStream_t stream) {
    const float* fb   = (const float*)d_in[0];
    const float* h    = (const float*)d_in[1];
    const float* t    = (const float*)d_in[2];
    const float* nz   = (const float*)d_in[3];
    const float* W1   = (const float*)d_in[4];
    const float* b1v  = (const float*)d_in[5];
    const float* W2   = (const float*)d_in[6];
    const float* b2v  = (const float*)d_in[7];
    const float* lpc  = (const float*)d_in[8];
    const float* envp = (const float*)d_in[9];
    const float* fade = (const float*)d_in[10];
    float* out = (float*)d_out;
    float* ws  = (float*)d_ws;

    if (ws_size < WS_NEED) {
        k_naive<<<1, 448, 0, stream>>>(fb, h, t, nz, W1, b1v, W2, b2v, lpc, envp, fade, out);
        return;
    }
    k_front<<<NB-1, 448, 0, stream>>>(fb, h, nz, W1, b1v, W2, b2v, lpc, ws);
    k_scan <<<1,    256, 0, stream>>>(h, W1, b1v, W2, b2v, ws);
    k_back <<<NB,   448, 0, stream>>>(fb, h, W1, b1v, W2, b2v, t, envp, fade, out, ws);
}

// Round 16
// 45.110 us; speedup vs baseline: 1.8115x; 1.2009x over previous
//
#include <hip/hip_runtime.h>
#include <utility>

#define N_SAMP   4410000
#define WSZ      441
#define NC       10000
#define NB       250
#define LB       40           // NB*LB == NC
#define HB       20           // half-block flush granularity
#define TILEF    (LB*WSZ)     // 17640 floats = per-block fb tile (70.6 KB)
#define RD       16           // Horner prefetch ring depth
#define TWO_PI_F 6.28318530717958647692f
#define FADE_START (N_SAMP - 256)
#define INV_SR   (1.0f/44100.0f)
#define INV441   (1.0f/441.0f)

// workspace layout (floats)
#define WS_WT   0                          // 441 wavetable (padded 448)
#define WS_SLOT(a) (448 + (a)*448)         // a = 0..NB-2: Vhat_a ([0..220]=Re, [224..444]=Im)
#define WS_NEED ((size_t)(448 + (NB-1)*448) * sizeof(float))

static_assert(NB * LB == NC, "block decomposition");
static_assert(LB == 2*HB, "two flush phases");

// ---- compile-time loop unroll (forces static indices -> registers, rule #20) ----
template <class F, int... Is>
__device__ __forceinline__ void unroll_impl(F f, std::integer_sequence<int, Is...>) {
    (f(std::integral_constant<int, Is>{}), ...);
}
template <int N, class F>
__device__ __forceinline__ void unroll_for(F f) {
    unroll_impl(f, std::make_integer_sequence<int, N>{});
}

// hardware trig: v_sin_f32/v_cos_f32 — input in REVOLUTIONS (sin/cos(2*pi*x)).
__device__ __forceinline__ float hwsin(float rev) { return __builtin_amdgcn_sinf(rev); }
__device__ __forceinline__ float hwcos(float rev) { return __builtin_amdgcn_cosf(rev); }

// async global->LDS: lane l copies 16B from its gsrc to ldsbase + l*16 (wave-uniform base).
__device__ __forceinline__ void gl2lds16(const float* gsrc_lane, float* lds_base_uniform) {
    __builtin_amdgcn_global_load_lds(
        (const __attribute__((address_space(1))) void*)gsrc_lane,
        (__attribute__((address_space(3))) void*)lds_base_uniform,
        16, 0, 0);
}

// stage nfloats from g to l using 7 waves (448 threads); caller must __syncthreads() after.
__device__ __forceinline__ void stage_tile7(const float* __restrict__ g,
                                            float* __restrict__ l,
                                            int nfloats, int tid) {
    const int wave = tid >> 6, lane = tid & 63;
    const int nfull = nfloats >> 8;              // 256-float (1 KiB) chunks
    for (int c = wave; c < nfull; c += 7)
        gl2lds16(g + (c << 8) + lane*4, l + (c << 8));
    const int rem = nfloats & 255;
    if (rem && wave == 0 && lane*4 < rem) {
        const int base = nfull << 8;
        gl2lds16(g + base + lane*4, l + base);
    }
}

__device__ __forceinline__ void bq_coefs(float f, float q,
    float& b0, float& b1, float& b2, float& a1, float& a2)
{
    float w0 = TWO_PI_F * f / 44100.0f;
    float cw = cosf(w0), sw = sinf(w0);
    float al = sw / (2.0f * q);
    float a0 = 1.0f + al;
    b0 = ((1.0f - cw) * 0.5f) / a0;
    b1 = (1.0f - cw) / a0;
    b2 = ((1.0f - cw) * 0.5f) / a0;
    a1 = (-2.0f * cw) / a0;
    a2 = (1.0f - al) / a0;
}

// serial biquad pair (fallback kernel only)
__device__ __forceinline__ void run_biquads(const float* __restrict__ noise,
    float lpf, float lpq, float f2, float* dst)
{
    float c10,c11,c12,c13,c14, c20,c21,c22,c23,c24;
    bq_coefs(lpf, lpq, c10,c11,c12,c13,c14);
    bq_coefs(f2, 0.707f, c20,c21,c22,c23,c24);
    float s11=0.f,s12=0.f,s21=0.f,s22=0.f;
    for (int m = 0; m < WSZ; ++m) {
        float x  = noise[m];
        float y1 = c10*x + s11;
        s11 = c11*x - c13*y1 + s12;
        s12 = c12*x - c14*y1;
        float y2 = c20*y1 + s21;
        s21 = c21*y1 - c23*y2 + s22;
        s22 = c22*y1 - c24*y2;
        dst[m] = y2;
    }
}

// redundant per-wave MLP: lane computes hid cols lane, lane+64; shfl_xor reduce -> lat[5]
__device__ __forceinline__ void mlp_latents(
    const float* __restrict__ h, const float* __restrict__ W1,
    const float* __restrict__ b1v, const float* __restrict__ W2,
    const float* __restrict__ b2v, int lane, float lat[5])
{
    float hc0 = b1v[lane], hc1 = b1v[lane + 64];
    #pragma unroll
    for (int i = 0; i < 9; ++i) {
        float hv = h[i];
        hc0 = fmaf(hv, W1[i*128 + lane], hc0);
        hc1 = fmaf(hv, W1[i*128 + lane + 64], hc1);
    }
    hc0 = fmaxf(hc0, 0.f); hc1 = fmaxf(hc1, 0.f);
    float part[5];
    #pragma unroll
    for (int m = 0; m < 5; ++m)
        part[m] = fmaf(hc0, W2[lane*5 + m], hc1 * W2[(lane+64)*5 + m]);
    #pragma unroll
    for (int off = 32; off > 0; off >>= 1) {
        #pragma unroll
        for (int m = 0; m < 5; ++m)
            part[m] += __shfl_xor(part[m], off);
    }
    #pragma unroll
    for (int m = 0; m < 5; ++m)
        lat[m] = fmaxf(part[m] + b2v[m], 0.f);
}

// wave-parallel biquad over 441 samples: lane l holds positions 7l..7l+6 (Kogge-Stone affine scan)
__device__ __forceinline__ void biquad_wave(const float xin[7], float yout[7],
    float f, float q, int l)
{
    float b0,b1,b2,a1,a2;
    bq_coefs(f, q, b0,b1,b2,a1,a2);
    const float t1c = b1 - a1*b0;
    const float t2c = b2 - a2*b0;
    float m00=1.f,m01=0.f,m10=0.f,m11=1.f;
    float cv0=0.f, cv1=0.f;
    #pragma unroll
    for (int k = 0; k < 7; ++k) {
        float x = xin[k];
        float n0 = -a1*cv0 + cv1 + t1c*x;
        float n1 = -a2*cv0 + t2c*x;
        cv0 = n0; cv1 = n1;
        float r00 = -a1*m00 + m10, r01 = -a1*m01 + m11;
        float r10 = -a2*m00,       r11 = -a2*m01;
        m00=r00; m01=r01; m10=r10; m11=r11;
    }
    #pragma unroll
    for (int d = 1; d < 64; d <<= 1) {
        int srcl = l - d; int s2 = srcl < 0 ? 0 : srcl;
        float pm00=__shfl(m00,s2), pm01=__shfl(m01,s2);
        float pm10=__shfl(m10,s2), pm11=__shfl(m11,s2);
        float pc0=__shfl(cv0,s2), pc1=__shfl(cv1,s2);
        if (srcl >= 0) {
            float nc0 = m00*pc0 + m01*pc1 + cv0;
            float nc1 = m10*pc0 + m11*pc1 + cv1;
            float n00 = m00*pm00 + m01*pm10;
            float n01 = m00*pm01 + m01*pm11;
            float n10 = m10*pm00 + m11*pm10;
            float n11 = m10*pm01 + m11*pm11;
            m00=n00; m01=n01; m10=n10; m11=n11; cv0=nc0; cv1=nc1;
        }
    }
    int esrc = (l == 0) ? 0 : l - 1;
    float e0 = __shfl(cv0, esrc);
    float e1 = __shfl(cv1, esrc);
    float s1  = (l == 0) ? 0.f : e0;
    float s2v = (l == 0) ? 0.f : e1;
    #pragma unroll
    for (int k = 0; k < 7; ++k) {
        float x = xin[k];
        float y = b0*x + s1;
        float ns1 = b1*x - a1*y + s2v;
        s2v = b2*x - a2*y;
        s1 = ns1;
        yout[k] = y;
    }
}

// ---------- 441-pt forward FFT (21x21 Cooley-Tukey), real input in v, modes 0..220 -> ws slot ----------
__device__ __forceinline__ void fft441_fwd(const float* v, float* Zr, float* Zi,
    const float* c441, const float* s441, float* ws_slot, int tid)
{
    if (tid < 441) {
        const int bq = tid / 21, c = tid - 21*bq;
        float yr = 0.f, yi = 0.f;
        int pm = 0;                                // (a*c) % 21
        #pragma unroll
        for (int a = 0; a < 21; ++a) {
            float x = v[21*a + bq];
            float cc = c441[21*pm], ss = s441[21*pm];
            yr = fmaf(x,  cc, yr);
            yi = fmaf(-x, ss, yi);
            pm += c; if (pm >= 21) pm -= 21;
        }
        const int bc = bq * c;                     // <= 400 < 441
        float cB = c441[bc], sB = s441[bc];
        Zr[c*21 + bq] = yr*cB + yi*sB;             // Z = Y * (cB - i sB)
        Zi[c*21 + bq] = yi*cB - yr*sB;
    }
    __syncthreads();
    if (tid < 441) {
        const int c = tid / 21, d = tid - 21*c;
        float xr = 0.f, xi = 0.f;
        int pm = 0;                                // (b*d) % 21
        const float* zr = Zr + c*21;
        const float* zi = Zi + c*21;
        #pragma unroll
        for (int bq = 0; bq < 21; ++bq) {
            float cc = c441[21*pm], ss = s441[21*pm];
            float gr = zr[bq], gi = zi[bq];
            xr = fmaf(gr, cc, fmaf(gi,  ss, xr));  // X += Z * (cc - i ss)
            xi = fmaf(gi, cc, fmaf(-gr, ss, xi));
            pm += d; if (pm >= 21) pm -= 21;
        }
        const int jm = c + 21*d;
        if (jm < 221) {
            ws_slot[jm]       = xr;
            ws_slot[224 + jm] = xi;
        }
    }
}

// ---------- 441-pt inverse FFT: full-spectrum S (conj-extended) -> real e_lds; scaled 1/441 ----------
__device__ __forceinline__ void fft441_inv(const float* SrF, const float* SiF,
    float* Hr, float* Hi, const float* c441, const float* s441,
    float* e_lds, int tid)
{
    if (tid < 441) {
        const int bq = tid / 21, c = tid - 21*bq;
        float gr = 0.f, gi = 0.f;
        int pm = 0;                                // (a*c) % 21
        #pragma unroll
        for (int a = 0; a < 21; ++a) {
            float sr = SrF[21*a + bq], si = SiF[21*a + bq];
            float cc = c441[21*pm], ss = s441[21*pm];
            gr = fmaf(sr, cc, fmaf(-si, ss, gr));  // G += S * (cc + i ss)
            gi = fmaf(sr, ss, fmaf( si, cc, gi));
            pm += c; if (pm >= 21) pm -= 21;
        }
        const int bc = bq * c;
        float cB = c441[bc], sB = s441[bc];
        Hr[c*21 + bq] = gr*cB - gi*sB;             // H = G * (cB + i sB)
        Hi[c*21 + bq] = gr*sB + gi*cB;
    }
    __syncthreads();
    if (tid < 441) {
        const int c = tid / 21, d = tid - 21*c;
        float acc = 0.f;
        int pm = 0;                                // (b*d) % 21
        const float* hr = Hr + c*21;
        const float* hi = Hi + c*21;
        #pragma unroll
        for (int bq = 0; bq < 21; ++bq) {
            float cc = c441[21*pm], ss = s441[21*pm];
            acc = fmaf(hr[bq], cc, fmaf(-hi[bq], ss, acc));  // Re(H * (cc + i ss))
            pm += d; if (pm >= 21) pm -= 21;
        }
        e_lds[c + 21*d] = acc * (1.0f/441.0f);
    }
}

// ============ kernel 1: whole-tile staging + local recurrence + forward FFT ============
__global__ __launch_bounds__(448, 1) void k_front(
    const float* __restrict__ fb, const float* __restrict__ h,
    const float* __restrict__ noise, const float* __restrict__ W1,
    const float* __restrict__ b1v, const float* __restrict__ W2,
    const float* __restrict__ b2v, const float* __restrict__ lpcut,
    float* __restrict__ ws)
{
    __shared__ __align__(16) float fbL[TILEF + 24];    // 70.7 KB
    __shared__ __align__(16) float v_lds[448];
    __shared__ __align__(16) float Zr[441], Zi[441];
    __shared__ float c441[441], s441[441];
    const int b = blockIdx.x;              // 0..NB-2
    const int tid = threadIdx.x;
    const bool w0 = tid < 64;
    const int j = tid;
    const bool act = w0 && (j < 63);
    const int i0 = b * LB;

    stage_tile7(fb + i0*WSZ, fbL, TILEF, tid);   // issue first; drains at 1st barrier
    if (tid < 441) {
        float ph = (float)tid * INV441;
        c441[tid] = hwcos(ph);
        s441[tid] = hwsin(ph);
    }

    float lat[5];
    mlp_latents(h, W1, b1v, W2, b2v, tid & 63, lat);
    const float decay = fminf(fmaxf(lat[0]/10.0f + 0.9f, 0.9f), 0.999f);
    const float famt  = lat[3];
    const float d2 = 0.5f * decay;
    const int src = (j == 0) ? 62 : j - 1;

    float cur[7];
    #pragma unroll
    for (int k = 0; k < 7; ++k) cur[k] = 0.f;
    if (w0 && b == 0) {
        const float lpf = fminf(fmaxf(lat[1]*44100.0f/4.0f, 100.0f), 22049.0f);
        const float lpq = fminf(fmaxf(lat[2], 0.1f), 0.999f);
        const float f2  = lpcut[0];
        float xin[7], y1[7], y2[7];
        #pragma unroll
        for (int k = 0; k < 7; ++k) xin[k] = act ? noise[7*j + k] : 0.f;
        biquad_wave(xin, y1, lpf, lpq, j);
        biquad_wave(y1, y2, f2, 0.707f, j);
        #pragma unroll
        for (int k = 0; k < 7; ++k) {
            cur[k] = act ? y2[k] : 0.f;
            if (act) ws[WS_WT + 7*j + k] = y2[k];
        }
    }
    __syncthreads();                           // staging drained; tables ready

    if (w0) {
        unroll_for<LB>([&](auto I) {
            constexpr int i = decltype(I)::value;
            float x[7];
            #pragma unroll
            for (int k = 0; k < 7; ++k) {
                float fv = act ? fbL[i*WSZ + 7*j + k] : 0.f;
                x[k] = fmaf(famt, fv, cur[k]);
            }
            float x6p = __shfl(x[6], src);     // pos 7j-1; lane0 <- lane62 (pos 440)
            cur[0] = d2 * (x[0] + x6p);
            #pragma unroll
            for (int k = 1; k < 7; ++k)
                cur[k] = d2 * (x[k] + x[k-1]);
        });
        if (act) {
            #pragma unroll
            for (int k = 0; k < 7; ++k) v_lds[7*j + k] = cur[k];
        }
    }
    __syncthreads();

    fft441_fwd(v_lds, Zr, Zi, c441, s441, ws + WS_SLOT(b), tid);
}

// ============ kernel 2: staging + per-block register Horner + inverse FFT + recurrence + env/flush ============
// Horner: S_b = sum_{a<b} P^{b-1-a} Vhat_a via S = P*S + Vhat_a. Coalesced per-thread ws reads,
// register ring RD deep. Replaces the serial k_scan stage (runs concurrently across blocks).
__global__ __launch_bounds__(448, 1) void k_back(
    const float* __restrict__ fb, const float* __restrict__ h,
    const float* __restrict__ W1, const float* __restrict__ b1v,
    const float* __restrict__ W2, const float* __restrict__ b2v,
    const float* __restrict__ t_in, const float* __restrict__ envp,
    const float* __restrict__ fade, float* __restrict__ out,
    const float* __restrict__ ws)
{
    __shared__ __align__(16) float fbL[TILEF + 24];    // 70.7 KB
    __shared__ float out_lds[HB*441];                  // 35.3 KB
    __shared__ __align__(16) float SrF[441], SiF[441];
    __shared__ __align__(16) float Hr[441], Hi[441];
    __shared__ __align__(16) float e_lds[448];
    __shared__ float c441[441], s441[441];
    const int b = blockIdx.x;                          // 0..NB-1
    const int tid = threadIdx.x;
    const bool w0 = tid < 64;
    const int j = tid;
    const bool act = w0 && (j < 63);
    const int i0 = b * LB;

    stage_tile7(fb + i0*WSZ, fbL, TILEF, tid);   // issue early; drains at barriers below
    if (tid < 441) {
        float ph = (float)tid * INV441;
        c441[tid] = hwcos(ph);
        s441[tid] = hwsin(ph);
    }

    float lat[5];
    mlp_latents(h, W1, b1v, W2, b2v, tid & 63, lat);
    const float decay = fminf(fmaxf(lat[0]/10.0f + 0.9f, 0.9f), 0.999f);
    const float famt  = lat[3];
    const float gain  = lat[4];
    const float d2 = 0.5f * decay;
    const int src = (j == 0) ? 62 : j - 1;

    if (b == 0) {
        for (int m = tid; m < 441; m += 448) e_lds[m] = ws[WS_WT + m];
        __syncthreads();
    } else {
        if (tid < 221) {
            // P = lambda^LB; lambda_j = d/2 (1 + e^{-2 pi i j/441})
            const float s = hwsin((float)tid * INV441);
            const float c = hwcos((float)tid * INV441);
            float lr = 0.5f*decay*(1.0f + c);
            float li = -0.5f*decay*s;
            float pr = 1.0f, pi = 0.0f, br = lr, bi = li;
            int e = LB;
            while (e) {
                if (e & 1) { float t = pr*br - pi*bi; pi = pr*bi + pi*br; pr = t; }
                float t2 = br*br - bi*bi; bi = 2.0f*br*bi; br = t2;
                e >>= 1;
            }
            // Horner over own predecessors, register ring RD deep (ws is L3-hot, reads coalesced)
            const int n = b;
            float sr = 0.f, si = 0.f;
            float cr[RD], ci[RD];
            #pragma unroll
            for (int d = 0; d < RD; ++d) {
                int idx = (d < n) ? d : n-1;
                cr[d] = ws[WS_SLOT(idx) + tid];
                ci[d] = ws[WS_SLOT(idx) + 224 + tid];
            }
            for (int base = 0; base < n; base += RD) {
                float nr[RD], ni[RD];
                #pragma unroll
                for (int d = 0; d < RD; ++d) {
                    int idx = base + RD + d; if (idx >= n) idx = n-1;
                    nr[d] = ws[WS_SLOT(idx) + tid];
                    ni[d] = ws[WS_SLOT(idx) + 224 + tid];
                }
                #pragma unroll
                for (int d = 0; d < RD; ++d) {
                    if (base + d < n) {
                        float t1 = fmaf(pr, sr, fmaf(-pi, si, cr[d]));
                        si = fmaf(pr, si, fmaf(pi, sr, ci[d]));
                        sr = t1;
                    }
                }
                #pragma unroll
                for (int d = 0; d < RD; ++d) { cr[d] = nr[d]; ci[d] = ni[d]; }
            }
            SrF[tid] = sr; SiF[tid] = si;
        }
        __syncthreads();
        if (tid >= 221 && tid < 441) {          // conj extension: S[j] = conj(S[441-j])
            SrF[tid] =  SrF[441 - tid];
            SiF[tid] = -SiF[441 - tid];
        }
        __syncthreads();
        fft441_inv(SrF, SiF, Hr, Hi, c441, s441, e_lds, tid);
        __syncthreads();
    }

    const float a_  = fabsf(envp[0]) + 1e-3f;
    const float sus = envp[1];
    const float rr  = fabsf(envp[2]) + 1e-3f;
    const float inv_a = 1.0f / a_;
    const float inv_r = 1.0f / rr;
    const float sg = sus * gain;
    const float T = t_in[N_SAMP - 1];

    float cur[7];
    #pragma unroll
    for (int k = 0; k < 7; ++k)
        cur[k] = act ? e_lds[7*j + k] : 0.f;

    auto compute_half = [&](auto PH) {
        constexpr int ph = decltype(PH)::value;
        if (w0) {
            unroll_for<HB>([&](auto I) {
                constexpr int il = decltype(I)::value;
                constexpr int i = ph*HB + il;
                float x[7];
                #pragma unroll
                for (int k = 0; k < 7; ++k) {
                    float fv = act ? fbL[i*WSZ + 7*j + k] : 0.f;
                    x[k] = fmaf(famt, fv, cur[k]);
                }
                float x6p = __shfl(x[6], src);
                cur[0] = d2 * (x[0] + x6p);
                #pragma unroll
                for (int k = 1; k < 7; ++k)
                    cur[k] = d2 * (x[k] + x[k-1]);
                if (act) {
                    #pragma unroll
                    for (int k = 0; k < 7; ++k)
                        out_lds[il*WSZ + 7*j + k] = cur[k];
                }
            });
        }
    };
    auto flush = [&](int ph) {
        const int s0 = (i0 + ph*HB) * WSZ;
        const float t_lo = (float)s0 * INV_SR;
        const float t_hi = (float)(s0 + HB*WSZ - 1) * INV_SR;
        const bool fastenv = (t_lo * inv_a >= 1.0f) &&
                             ((T - t_hi) * inv_r >= 1.0f) &&
                             (s0 + HB*WSZ <= FADE_START);
        if (fastenv) {
            for (int e = tid; e < HB*WSZ; e += 448)
                out[s0 + e] = out_lds[e] * sg;
        } else {
            for (int e = tid; e < HB*WSZ; e += 448) {
                const int idx = s0 + e;
                float tt = (float)idx * INV_SR;           // exact int->float: idx < 2^23
                float ca  = fminf(tt * inv_a, 1.0f);
                float crr = fminf(fmaxf((T - tt) * inv_r, 0.0f), 1.0f);
                float val = out_lds[e] * (ca * crr * sg);
                if (idx >= FADE_START) val *= fade[idx - FADE_START];
                out[idx] = val;
            }
        }
    };

    compute_half(std::integral_constant<int,0>{});
    __syncthreads();
    flush(0);
    __syncthreads();
    compute_half(std::integral_constant<int,1>{});
    __syncthreads();
    flush(1);
}

// ---------------- fallback: fully sequential single block (no workspace) ----------
__global__ __launch_bounds__(448) void k_naive(
    const float* __restrict__ fb, const float* __restrict__ h,
    const float* __restrict__ t_in, const float* __restrict__ noise,
    const float* __restrict__ W1, const float* __restrict__ b1v,
    const float* __restrict__ W2, const float* __restrict__ b2v,
    const float* __restrict__ lpcut, const float* __restrict__ envp,
    const float* __restrict__ fade, float* __restrict__ out)
{
    __shared__ float hid[128];
    __shared__ float lat[5];
    __shared__ float wt[WSZ];
    __shared__ float buf[2][448];
    const int j = threadIdx.x;
    if (j < 128) {
        float acc = b1v[j];
        #pragma unroll
        for (int i = 0; i < 9; ++i) acc = acc + h[i] * W1[i*128 + j];
        hid[j] = fmaxf(acc, 0.0f);
    }
    __syncthreads();
    if (j < 5) {
        float a = b2v[j];
        for (int k = 0; k < 128; ++k) a = a + hid[k] * W2[k*5 + j];
        lat[j] = fmaxf(a, 0.0f);
    }
    __syncthreads();
    if (j == 0) {
        float lpf = fminf(fmaxf(lat[1]*44100.0f/4.0f, 100.0f), 22049.0f);
        float lpq = fminf(fmaxf(lat[2], 0.1f), 0.999f);
        run_biquads(noise, lpf, lpq, lpcut[0], wt);
    }
    __syncthreads();
    const float decay = fminf(fmaxf(lat[0]/10.0f + 0.9f, 0.9f), 0.999f);
    const float famt = lat[3];
    const float gain = lat[4];
    const float d2 = 0.5f * decay;
    const float a_  = fabsf(envp[0]) + 1e-3f;
    const float sus = envp[1];
    const float rr  = fabsf(envp[2]) + 1e-3f;
    const float inv_a = 1.0f / a_, inv_r = 1.0f / rr;
    const float T = t_in[N_SAMP - 1];
    const bool act = j < WSZ;
    const int jm1 = (j == 0) ? (WSZ - 1) : (j - 1);
    float cur = act ? wt[j] : 0.0f;
    for (int i = 0; i < NC; ++i) {
        float x = cur + famt * (act ? fb[i*WSZ + j] : 0.0f);
        buf[i&1][j] = x;
        __syncthreads();
        cur = d2 * (x + buf[i&1][jm1]);
        const int idx = i*WSZ + j;
        float val = cur;
        if (idx >= FADE_START) val *= fade[idx - FADE_START];
        float tt = act ? t_in[idx] : 0.0f;
        float ca  = fminf(fmaxf(tt * inv_a, 0.0f), 1.0f);
        float cr2 = fminf(fmaxf((T - tt) * inv_r, 0.0f), 1.0f);
        val = val * (ca * cr2 * sus) * gain;
        if (act) out[idx] = val;
    }
}

extern "C" void kernel_launch(void* const* d_in, const int* in_sizes, int n_in,
                              void* d_out, int out_size, void* d_ws, size_t ws_size,
                              hipStream_t stream) {
    const float* fb   = (const float*)d_in[0];
    const float* h    = (const float*)d_in[1];
    const float* t    = (const float*)d_in[2];
    const float* nz   = (const float*)d_in[3];
    const float* W1   = (const float*)d_in[4];
    const float* b1v  = (const float*)d_in[5];
    const float* W2   = (const float*)d_in[6];
    const float* b2v  = (const float*)d_in[7];
    const float* lpc  = (const float*)d_in[8];
    const float* envp = (const float*)d_in[9];
    const float* fade = (const float*)d_in[10];
    float* out = (float*)d_out;
    float* ws  = (float*)d_ws;

    if (ws_size < WS_NEED) {
        k_naive<<<1, 448, 0, stream>>>(fb, h, t, nz, W1, b1v, W2, b2v, lpc, envp, fade, out);
        return;
    }
    k_front<<<NB-1, 448, 0, stream>>>(fb, h, nz, W1, b1v, W2, b2v, lpc, ws);
    k_back <<<NB,   448, 0, stream>>>(fb, h, W1, b1v, W2, b2v, t, envp, fade, out, ws);
}